// Round 1
// baseline (569.196 us; speedup 1.0000x reference)
//
#include <hip/hip_runtime.h>

// KPN-style per-pixel dynamic 5x5 conv:
//   out[b,n,h,w] = W[b,n,h,w] * sum_{i,j} core[b, n*25+i*5+j, h, w] * frames_zp[b,n,h+i-2,w+j-2]
// Memory-bound: core (419 MB) streams once; frames staged per-row in LDS.

#define KK   5
#define PADR 2
#define BB   2
#define NN   8
#define HH   512
#define WW   512

constexpr int SROW    = WW + 2 * PADR;  // 516 staged columns per row
constexpr int SSTRIDE = SROW + 4;       // 520 (keep rows aligned-ish)

__global__ __launch_bounds__(128) void kpn_kernel(
    const float* __restrict__ frames,
    const float* __restrict__ core,
    const float* __restrict__ Wt,
    float* __restrict__ out)
{
    __shared__ float smem[KK * SSTRIDE];

    const int tid = threadIdx.x;
    const int h   = blockIdx.x % HH;
    const int bn  = blockIdx.x / HH;  // b*N + n

    // ---- stage 5 frame rows (h-2..h+2) into LDS with zero halo ----
    const float* fbase = frames + (size_t)bn * HH * WW;
    #pragma unroll
    for (int i = 0; i < KK; ++i) {
        const int  row = h - PADR + i;
        const bool rok = (row >= 0) && (row < HH);
        const float* frow = fbase + (size_t)row * WW;
        for (int idx = tid; idx < SROW; idx += 128) {
            const int x = idx - PADR;
            float v = 0.0f;
            if (rok && x >= 0 && x < WW) v = frow[x];
            smem[i * SSTRIDE + idx] = v;
        }
    }
    __syncthreads();

    const int w0 = tid * 4;  // 128 threads x 4 = 512 columns

    // register window: rows 0..4, smem cols w0..w0+7  (= frame cols w0-2..w0+5)
    float fr[KK][8];
    #pragma unroll
    for (int i = 0; i < KK; ++i) {
        #pragma unroll
        for (int t = 0; t < 8; ++t)
            fr[i][t] = smem[i * SSTRIDE + w0 + t];
    }

    float acc0 = 0.f, acc1 = 0.f, acc2 = 0.f, acc3 = 0.f;

    // core channel base: channel index = bn*25 + c   (c = i*5+j)
    const float* cbase = core + ((size_t)bn * (KK * KK) * HH + h) * WW + w0;
    #pragma unroll
    for (int i = 0; i < KK; ++i) {
        #pragma unroll
        for (int j = 0; j < KK; ++j) {
            const int c = i * KK + j;
            const float4 cv = *(const float4*)(cbase + (size_t)c * HH * WW);
            acc0 += cv.x * fr[i][j + 0];
            acc1 += cv.y * fr[i][j + 1];
            acc2 += cv.z * fr[i][j + 2];
            acc3 += cv.w * fr[i][j + 3];
        }
    }

    const size_t o  = ((size_t)bn * HH + h) * WW + w0;
    const float4 wv = *(const float4*)(Wt + o);
    float4 ov;
    ov.x = wv.x * acc0;
    ov.y = wv.y * acc1;
    ov.z = wv.z * acc2;
    ov.w = wv.w * acc3;
    *(float4*)(out + o) = ov;
}

extern "C" void kernel_launch(void* const* d_in, const int* in_sizes, int n_in,
                              void* d_out, int out_size, void* d_ws, size_t ws_size,
                              hipStream_t stream)
{
    const float* frames = (const float*)d_in[0];
    const float* core   = (const float*)d_in[1];
    const float* Wt     = (const float*)d_in[2];
    float*       out    = (float*)d_out;

    const dim3 grid(BB * NN * HH);  // 8192 blocks, one (b,n,h) row each
    kpn_kernel<<<grid, 128, 0, stream>>>(frames, core, Wt, out);
}

// Round 3
// 539.096 us; speedup vs baseline: 1.0558x; 1.0558x over previous
//
#include <hip/hip_runtime.h>

// KPN-style per-pixel dynamic 5x5 conv:
//   out[b,n,h,w] = W[b,n,h,w] * sum_{i,j} core[b, n*25+i*5+j, h, w] * frames_zp[b,n,h+i-2,w+j-2]
//
// R3: same as R2 but nontemporal builtins use clang ext_vector_type (HIP's
// float4 class type is rejected by __builtin_nontemporal_*).

#define KK   5
#define BB   2
#define NN   8
#define HH   512
#define WW   512

typedef float  v4f __attribute__((ext_vector_type(4)));
typedef float  v2f __attribute__((ext_vector_type(2)));

__global__ __launch_bounds__(128) void kpn_kernel(
    const float* __restrict__ frames,
    const float* __restrict__ core,
    const float* __restrict__ Wt,
    float* __restrict__ out)
{
    const int tid = threadIdx.x;
    const int h   = blockIdx.x;   // 0..511
    const int bn  = blockIdx.y;   // 0..15 (b*N + n)
    const int w0  = tid * 4;      // 128 threads x 4 cols = 512

    const bool has_left  = (tid != 0);
    const bool has_right = (tid != 127);

    const float* fbase = frames + (size_t)bn * HH * WW;

    float acc0 = 0.f, acc1 = 0.f, acc2 = 0.f, acc3 = 0.f;

    // core channel base for c=0; channels stride HH*WW floats
    const float* cbase = core + ((size_t)bn * (KK * KK) * HH + h) * WW + w0;

    #pragma unroll
    for (int i = 0; i < KK; ++i) {
        const int  r   = h - 2 + i;
        const bool rok = (r >= 0) && (r < HH);
        const float* rp = fbase + (size_t)r * WW + w0;

        v2f a = {0.f, 0.f};
        v4f b = {0.f, 0.f, 0.f, 0.f};
        v2f c = {0.f, 0.f};
        if (rok) {
            b = *(const v4f*)(rp);
            if (has_left)  a = *(const v2f*)(rp - 2);
            if (has_right) c = *(const v2f*)(rp + 4);
        }
        // frw[t] = frame col w0-2+t :  a.x a.y | b.x b.y b.z b.w | c.x c.y
        const float frw[8] = {a.x, a.y, b.x, b.y, b.z, b.w, c.x, c.y};

        #pragma unroll
        for (int j = 0; j < KK; ++j) {
            const int ch = i * KK + j;
            const v4f cv = __builtin_nontemporal_load(
                (const v4f*)(cbase + (size_t)ch * HH * WW));
            acc0 += cv.x * frw[j + 0];
            acc1 += cv.y * frw[j + 1];
            acc2 += cv.z * frw[j + 2];
            acc3 += cv.w * frw[j + 3];
        }
    }

    const size_t o  = ((size_t)bn * HH + h) * WW + w0;
    const v4f wv = __builtin_nontemporal_load((const v4f*)(Wt + o));
    v4f ov;
    ov.x = wv.x * acc0;
    ov.y = wv.y * acc1;
    ov.z = wv.z * acc2;
    ov.w = wv.w * acc3;
    __builtin_nontemporal_store(ov, (v4f*)(out + o));
}

extern "C" void kernel_launch(void* const* d_in, const int* in_sizes, int n_in,
                              void* d_out, int out_size, void* d_ws, size_t ws_size,
                              hipStream_t stream)
{
    const float* frames = (const float*)d_in[0];
    const float* core   = (const float*)d_in[1];
    const float* Wt     = (const float*)d_in[2];
    float*       out    = (float*)d_out;

    dim3 grid(HH, BB * NN);  // (h, b*N+n)
    kpn_kernel<<<grid, 128, 0, stream>>>(frames, core, Wt, out);
}